// Round 6
// baseline (81.271 us; speedup 1.0000x reference)
//
#include <hip/hip_runtime.h>
#include <hip/hip_cooperative_groups.h>

namespace cg = cooperative_groups;

// TBSyntaxParser v6: ONE cooperative kernel. Phase 1 packs W1 -> bf16
// B-fragments (156 waves) while ALL blocks gather X -> LDS A-fragments and
// write the legal mask; grid.sync() orders bfrag and doubles as the block
// barrier; phase 2 prefetches B (24 coalesced 16B loads issued together),
// runs MFMA layer-1 and the fused in-register layer-2 epilogue.
// B=4096, L=128, D=60, X=360(k, pad 384), HID=200(n, pad 208), OUT=3.
// d_out = [out (B*3) | legal (B*3)] f32.

#define Bq    4096
#define Lq    128
#define Dq    60
#define HIDq  200
#define ONUM  3
#define KTN   12      // k-tiles (384/32)
#define NTN   13      // n-tiles (208/16)
#define MB    16      // states per block (MFMA M)
#define NTHR  512     // 8 waves
#define NBLK  (Bq / MB)   // 256 blocks

typedef short bf16x8 __attribute__((ext_vector_type(8)));
typedef float f32x4  __attribute__((ext_vector_type(4)));

__device__ __forceinline__ unsigned int rhu(float f) {
    union { float f; unsigned int u; } x; x.f = f;
    return x.u + 0x8000u;                      // round-half-up into bf16 slot
}
// pack two rounded floats -> (bf16(hi)<<16) | bf16(lo) in one v_perm_b32
__device__ __forceinline__ int pack2(float lo, float hi) {
    return (int)__builtin_amdgcn_perm(rhu(hi), rhu(lo), 0x07060302u);
}

__global__ __launch_bounds__(NTHR, 2) void parser_coop(
    const float* __restrict__ buffer,
    const float* __restrict__ W1,
    const float* __restrict__ b1,
    const float* __restrict__ W2,
    const float* __restrict__ b2,
    const int*   __restrict__ buffer_index,
    const int*   __restrict__ stack_indexes,
    const int*   __restrict__ stack_len,
    float*       __restrict__ out,
    unsigned short* __restrict__ bfrag)
{
    __shared__ unsigned short Afrag[KTN * 64 * 8];   // 12 KiB, A-fragment packed
    __shared__ float psum[8][MB][ONUM];              // 1.5 KiB wave partials

    const int t  = threadIdx.x;
    const int w  = t >> 6;
    const int l  = t & 63;
    const int s0 = blockIdx.x * MB;

    // ================= PHASE 1 =================
    // ---- W1 pack: global wave id gw packs fragment tile gw (156 tiles) ----
    // bfrag[((kt*NTN+nt)*64+lane)*8+e] = bf16(W1[kt*32+(lane>>4)*8+e][nt*16+(lane&15)])
    {
        int gw = blockIdx.x * 8 + w;
        if (gw < KTN * NTN) {
            int kt = gw / NTN, nt = gw % NTN;
            int kb = kt * 32 + (l >> 4) * 8;
            int n  = nt * 16 + (l & 15);
            bf16x8 pk;
            #pragma unroll
            for (int e = 0; e < 8; ++e) {
                int k = kb + e;
                float f = (k < 360 && n < HIDq) ? W1[k * HIDq + n] : 0.f;
                pk[e] = (short)(unsigned short)(rhu(f) >> 16);
            }
            *((bf16x8*)(bfrag + ((size_t)gw * 64 + l) * 8)) = pk;
        }
    }

    // ---- gather X: 1440 float4 jobs over 512 threads ----
    // X[s][k] -> kt=k>>5, lane = s + ((k&31)>>3)*16, e = k&7  (k0%4==0 per job)
    #define GATHER_JOB(i)                                                        \
    {                                                                            \
        int s = (i) / 90, r = (i) % 90, seg = r / 15, f = r % 15;                \
        int row = (seg < 3) ? (buffer_index[s0 + s] + seg)                       \
                            : stack_indexes[(s0 + s) * 3 + (seg - 3)];           \
        float4 v = ((const float4*)(buffer + ((size_t)(s0 + s) * Lq + row) * Dq))[f]; \
        int k0   = seg * 60 + f * 4;                                             \
        int kt   = k0 >> 5;                                                      \
        int lane = s + (((k0 & 31) >> 3) << 4);                                  \
        uint2 pk;                                                                \
        pk.x = (unsigned)pack2(v.x, v.y);                                        \
        pk.y = (unsigned)pack2(v.z, v.w);                                        \
        *((uint2*)&Afrag[(size_t)(kt * 64 + lane) * 8 + (k0 & 7)]) = pk;         \
    }
    GATHER_JOB(t)
    GATHER_JOB(t + 512)
    if (t < 416) GATHER_JOB(t + 1024)
    #undef GATHER_JOB

    // zero k-pad of kt=11 (lanes 16..63 hold k in [360,384))
    if (t < 48) {
        f32x4 z = {0.f, 0.f, 0.f, 0.f};
        *((f32x4*)&Afrag[(size_t)(11 * 64 + 16 + t) * 8]) = z;
    }

    // ---- epilogue constants (independent of bfrag) ----
    const int  n0    = w * 16 + (l & 15);            // <= 127, always valid
    const bool hasB1 = (w < 5);
    const int  n1    = (8 + w) * 16 + (l & 15);
    const bool n1ok  = n1 < HIDq;

    float bb0 = b1[n0];
    float w20 = W2[n0 * ONUM + 0], w21 = W2[n0 * ONUM + 1], w22 = W2[n0 * ONUM + 2];
    float bb1 = 0.f, w23 = 0.f, w24 = 0.f, w25 = 0.f;
    if (hasB1 && n1ok) {
        bb1 = b1[n1];
        w23 = W2[n1 * ONUM + 0]; w24 = W2[n1 * ONUM + 1]; w25 = W2[n1 * ONUM + 2];
    }

    // ---- legal mask (independent of MLP) ----
    if (t < MB * ONUM) {
        int s = t / ONUM, o = t % ONUM;
        int bi = buffer_index[s0 + s];
        int sl = stack_len[s0 + s];
        float lg;
        if (o == 0)      lg = (bi + 3 >= Lq) ? 0.f : 1.f;
        else if (o == 1) lg = (sl <= 3)      ? 0.f : 1.f;
        else             lg = (sl <= 4)      ? 0.f : 1.f;
        out[(size_t)Bq * ONUM + (size_t)(s0 + s) * ONUM + o] = lg;
    }

    // ---- device-scope ordering of bfrag writes, then grid barrier ----
    __threadfence();
    cg::this_grid().sync();

    // ================= PHASE 2 =================
    // ---- B-fragment loads: all 24 coalesced 16B loads issued up-front ----
    bf16x8 B0[KTN], B1[KTN];
    #pragma unroll
    for (int kt = 0; kt < KTN; ++kt)
        B0[kt] = *((const bf16x8*)(bfrag + ((size_t)(kt * NTN + w) * 64 + l) * 8));
    if (hasB1) {
        #pragma unroll
        for (int kt = 0; kt < KTN; ++kt)
            B1[kt] = *((const bf16x8*)(bfrag + ((size_t)(kt * NTN + 8 + w) * 64 + l) * 8));
    }

    // ---- layer 1 MFMA: A from LDS, B in registers ----
    f32x4 acc0 = {}, acc1 = {};
    #pragma unroll
    for (int kt = 0; kt < KTN; ++kt) {
        bf16x8 a = *((const bf16x8*)&Afrag[(size_t)(kt * 64 + l) * 8]);
        acc0 = __builtin_amdgcn_mfma_f32_16x16x32_bf16(a, B0[kt], acc0, 0, 0, 0);
        if (hasB1)
            acc1 = __builtin_amdgcn_mfma_f32_16x16x32_bf16(a, B1[kt], acc1, 0, 0, 0);
    }

    // ---- fused epilogue: bias + ReLU + layer-2 partials in-register ----
    // lane holds hid_pre[s = (l>>4)*4 + r][j = nt*16 + (l&15)] in acc[r]
    float p[ONUM][4];
    #pragma unroll
    for (int o = 0; o < ONUM; ++o)
        #pragma unroll
        for (int r = 0; r < 4; ++r) p[o][r] = 0.f;

    #pragma unroll
    for (int r = 0; r < 4; ++r) {
        float h = acc0[r] + bb0; h = h > 0.f ? h : 0.f;
        p[0][r] = fmaf(h, w20, p[0][r]);
        p[1][r] = fmaf(h, w21, p[1][r]);
        p[2][r] = fmaf(h, w22, p[2][r]);
    }
    if (hasB1) {
        #pragma unroll
        for (int r = 0; r < 4; ++r) {
            float h = acc1[r] + bb1; h = h > 0.f ? h : 0.f;   // consts are 0 if n1>=200
            p[0][r] = fmaf(h, w23, p[0][r]);
            p[1][r] = fmaf(h, w24, p[1][r]);
            p[2][r] = fmaf(h, w25, p[2][r]);
        }
    }

    // butterfly-reduce over the 16-lane j-group
    #pragma unroll
    for (int d = 1; d < 16; d <<= 1) {
        #pragma unroll
        for (int o = 0; o < ONUM; ++o)
            #pragma unroll
            for (int r = 0; r < 4; ++r)
                p[o][r] += __shfl_xor(p[o][r], d, 64);
    }
    if ((l & 15) == 0) {
        #pragma unroll
        for (int r = 0; r < 4; ++r) {
            int s = ((l >> 4) << 2) + r;
            #pragma unroll
            for (int o = 0; o < ONUM; ++o) psum[w][s][o] = p[o][r];
        }
    }
    __syncthreads();

    // ---- combine 8 wave-partials + bias ----
    if (t < MB * ONUM) {
        int s = t / ONUM, o = t % ONUM;
        float v = b2[o];
        #pragma unroll
        for (int w8 = 0; w8 < 8; ++w8) v += psum[w8][s][o];
        out[(size_t)(s0 + s) * ONUM + o] = v;
    }
}

extern "C" void kernel_launch(void* const* d_in, const int* in_sizes, int n_in,
                              void* d_out, int out_size, void* d_ws, size_t ws_size,
                              hipStream_t stream) {
    const float* buffer        = (const float*)d_in[0];
    const float* W1            = (const float*)d_in[1];
    const float* b1            = (const float*)d_in[2];
    const float* W2            = (const float*)d_in[3];
    const float* b2            = (const float*)d_in[4];
    const int*   buffer_index  = (const int*)d_in[5];
    const int*   stack_indexes = (const int*)d_in[6];
    const int*   stack_len     = (const int*)d_in[7];
    float*       out           = (float*)d_out;
    unsigned short* bfrag      = (unsigned short*)d_ws;   // 156*64*8*2 = 159,744 B

    void* args[] = {
        (void*)&buffer, (void*)&W1, (void*)&b1, (void*)&W2, (void*)&b2,
        (void*)&buffer_index, (void*)&stack_indexes, (void*)&stack_len,
        (void*)&out, (void*)&bfrag
    };
    hipLaunchCooperativeKernel((const void*)parser_coop,
                               dim3(NBLK), dim3(NTHR), args, 0, stream);
}

// Round 7
// 15.592 us; speedup vs baseline: 5.2124x; 5.2124x over previous
//
#include <hip/hip_runtime.h>

// TBSyntaxParser v7: v5 two-kernel structure + forced pre-barrier
// materialization of B-fragments (asm keepalives) so B-load latency is
// fully hidden under the gather phase instead of being re-sunk into the
// MFMA loop by the compiler.
// B=4096, L=128, D=60, X=360(k, pad 384), HID=200(n, pad 208), OUT=3.
// d_out = [out (B*3) | legal (B*3)] f32.

#define Bq    4096
#define Lq    128
#define Dq    60
#define HIDq  200
#define ONUM  3
#define KTN   12      // k-tiles (384/32)
#define NTN   13      // n-tiles (208/16)
#define MB    16      // states per block (MFMA M)
#define NTHR  512     // 8 waves

typedef short bf16x8 __attribute__((ext_vector_type(8)));
typedef float f32x4  __attribute__((ext_vector_type(4)));

__device__ __forceinline__ unsigned int rhu(float f) {
    union { float f; unsigned int u; } x; x.f = f;
    return x.u + 0x8000u;                      // round-half-up into bf16 slot
}
// pack two rounded floats -> (bf16(hi)<<16) | bf16(lo) in one v_perm_b32
__device__ __forceinline__ int pack2(float lo, float hi) {
    return (int)__builtin_amdgcn_perm(rhu(hi), rhu(lo), 0x07060302u);
}

// ---- prep: W1 [360][200] f32 -> B-fragment-packed bf16 in ws ----
// bfrag[((kt*NTN+nt)*64 + lane)*8 + e] = bf16(W1[kt*32+(lane>>4)*8+e][nt*16+(lane&15)])
__global__ __launch_bounds__(256) void prep_w1(const float* __restrict__ W1,
                                               unsigned short* __restrict__ bfrag) {
    int fid = blockIdx.x * 4 + (threadIdx.x >> 6);   // 39*4 = 156 fragment tiles
    int kt  = fid / NTN, nt = fid % NTN;
    int l   = threadIdx.x & 63;
    int kb  = kt * 32 + (l >> 4) * 8;
    int n   = nt * 16 + (l & 15);
    bf16x8 pack;
    #pragma unroll
    for (int e = 0; e < 8; ++e) {
        int k = kb + e;
        float f = (k < 360 && n < HIDq) ? W1[k * HIDq + n] : 0.f;
        pack[e] = (short)(unsigned short)(rhu(f) >> 16);
    }
    *((bf16x8*)(bfrag + ((size_t)fid * 64 + l) * 8)) = pack;
}

__global__ __launch_bounds__(NTHR, 2) void parser_main(
    const float* __restrict__ buffer,
    const unsigned short* __restrict__ bfrag,
    const float* __restrict__ b1,
    const float* __restrict__ W2,
    const float* __restrict__ b2,
    const int*   __restrict__ buffer_index,
    const int*   __restrict__ stack_indexes,
    const int*   __restrict__ stack_len,
    float*       __restrict__ out)
{
    __shared__ unsigned short Afrag[KTN * 64 * 8];   // 12 KiB, A-fragment packed
    __shared__ float psum[8][MB][ONUM];              // 1.5 KiB wave partials

    const int t  = threadIdx.x;
    const int w  = t >> 6;
    const int l  = t & 63;
    const int s0 = blockIdx.x * MB;

    // ---- B-fragment prefetch: 24 coalesced 16B loads issued first ----
    const int  n0    = w * 16 + (l & 15);            // <= 127, always valid
    const bool hasB1 = (w < 5);
    const int  n1    = (8 + w) * 16 + (l & 15);
    const bool n1ok  = n1 < HIDq;

    bf16x8 B0[KTN], B1[KTN];
    #pragma unroll
    for (int kt = 0; kt < KTN; ++kt)
        B0[kt] = *((const bf16x8*)(bfrag + ((size_t)(kt * NTN + w) * 64 + l) * 8));
    if (hasB1) {
        #pragma unroll
        for (int kt = 0; kt < KTN; ++kt)
            B1[kt] = *((const bf16x8*)(bfrag + ((size_t)(kt * NTN + 8 + w) * 64 + l) * 8));
    }

    // ---- epilogue constants, also pre-barrier ----
    float bb0 = b1[n0];
    float w20 = W2[n0 * ONUM + 0], w21 = W2[n0 * ONUM + 1], w22 = W2[n0 * ONUM + 2];
    float bb1 = 0.f, w23 = 0.f, w24 = 0.f, w25 = 0.f;
    if (hasB1 && n1ok) {
        bb1 = b1[n1];
        w23 = W2[n1 * ONUM + 0]; w24 = W2[n1 * ONUM + 1]; w25 = W2[n1 * ONUM + 2];
    }

    // ---- gather X: 1440 float4 jobs over 512 threads ----
    // X[s][k] -> kt=k>>5, lane = s + ((k&31)>>3)*16, e = k&7  (k0%4==0 per job)
    #define GATHER_JOB(i)                                                        \
    {                                                                            \
        int s = (i) / 90, r = (i) % 90, seg = r / 15, f = r % 15;                \
        int row = (seg < 3) ? (buffer_index[s0 + s] + seg)                       \
                            : stack_indexes[(s0 + s) * 3 + (seg - 3)];           \
        float4 v = ((const float4*)(buffer + ((size_t)(s0 + s) * Lq + row) * Dq))[f]; \
        int k0   = seg * 60 + f * 4;                                             \
        int kt   = k0 >> 5;                                                      \
        int lane = s + (((k0 & 31) >> 3) << 4);                                  \
        uint2 pk;                                                                \
        pk.x = (unsigned)pack2(v.x, v.y);                                        \
        pk.y = (unsigned)pack2(v.z, v.w);                                        \
        *((uint2*)&Afrag[(size_t)(kt * 64 + lane) * 8 + (k0 & 7)]) = pk;         \
    }
    GATHER_JOB(t)
    GATHER_JOB(t + 512)
    if (t < 416) GATHER_JOB(t + 1024)
    #undef GATHER_JOB

    // zero k-pad of kt=11 (lanes 16..63 hold k in [360,384))
    if (t < 48) {
        f32x4 z = {0.f, 0.f, 0.f, 0.f};
        *((f32x4*)&Afrag[(size_t)(11 * 64 + 16 + t) * 8]) = z;
    }

    // ---- legal mask (independent of MLP) ----
    if (t < MB * ONUM) {
        int s = t / ONUM, o = t % ONUM;
        int bi = buffer_index[s0 + s];
        int sl = stack_len[s0 + s];
        float lg;
        if (o == 0)      lg = (bi + 3 >= Lq) ? 0.f : 1.f;
        else if (o == 1) lg = (sl <= 3)      ? 0.f : 1.f;
        else             lg = (sl <= 4)      ? 0.f : 1.f;
        out[(size_t)Bq * ONUM + (size_t)(s0 + s) * ONUM + o] = lg;
    }

    // ---- force B-fragments resident in VGPRs BEFORE the barrier ----
    // (the implied vmcnt wait lands where the barrier would wait anyway;
    //  prevents the compiler sinking these loads into the MFMA loop)
    #pragma unroll
    for (int kt = 0; kt < KTN; ++kt) {
        asm volatile("" :: "v"(B0[kt]));
        if (hasB1) asm volatile("" :: "v"(B1[kt]));
    }
    __syncthreads();

    // ---- layer 1 MFMA: A from LDS, B already in registers ----
    f32x4 acc0 = {}, acc1 = {};
    #pragma unroll
    for (int kt = 0; kt < KTN; ++kt) {
        bf16x8 a = *((const bf16x8*)&Afrag[(size_t)(kt * 64 + l) * 8]);
        acc0 = __builtin_amdgcn_mfma_f32_16x16x32_bf16(a, B0[kt], acc0, 0, 0, 0);
        if (hasB1)
            acc1 = __builtin_amdgcn_mfma_f32_16x16x32_bf16(a, B1[kt], acc1, 0, 0, 0);
    }

    // ---- fused epilogue: bias + ReLU + layer-2 partials in-register ----
    // lane holds hid_pre[s = (l>>4)*4 + r][j = nt*16 + (l&15)] in acc[r]
    float p[ONUM][4];
    #pragma unroll
    for (int o = 0; o < ONUM; ++o)
        #pragma unroll
        for (int r = 0; r < 4; ++r) p[o][r] = 0.f;

    #pragma unroll
    for (int r = 0; r < 4; ++r) {
        float h = acc0[r] + bb0; h = h > 0.f ? h : 0.f;
        p[0][r] = fmaf(h, w20, p[0][r]);
        p[1][r] = fmaf(h, w21, p[1][r]);
        p[2][r] = fmaf(h, w22, p[2][r]);
    }
    if (hasB1) {
        #pragma unroll
        for (int r = 0; r < 4; ++r) {
            float h = acc1[r] + bb1; h = h > 0.f ? h : 0.f;   // consts are 0 if n1>=200
            p[0][r] = fmaf(h, w23, p[0][r]);
            p[1][r] = fmaf(h, w24, p[1][r]);
            p[2][r] = fmaf(h, w25, p[2][r]);
        }
    }

    // butterfly-reduce over the 16-lane j-group
    #pragma unroll
    for (int d = 1; d < 16; d <<= 1) {
        #pragma unroll
        for (int o = 0; o < ONUM; ++o)
            #pragma unroll
            for (int r = 0; r < 4; ++r)
                p[o][r] += __shfl_xor(p[o][r], d, 64);
    }
    if ((l & 15) == 0) {
        #pragma unroll
        for (int r = 0; r < 4; ++r) {
            int s = ((l >> 4) << 2) + r;
            #pragma unroll
            for (int o = 0; o < ONUM; ++o) psum[w][s][o] = p[o][r];
        }
    }
    __syncthreads();

    // ---- combine 8 wave-partials + bias ----
    if (t < MB * ONUM) {
        int s = t / ONUM, o = t % ONUM;
        float v = b2[o];
        #pragma unroll
        for (int w8 = 0; w8 < 8; ++w8) v += psum[w8][s][o];
        out[(size_t)(s0 + s) * ONUM + o] = v;
    }
}

extern "C" void kernel_launch(void* const* d_in, const int* in_sizes, int n_in,
                              void* d_out, int out_size, void* d_ws, size_t ws_size,
                              hipStream_t stream) {
    const float* buffer        = (const float*)d_in[0];
    const float* W1            = (const float*)d_in[1];
    const float* b1            = (const float*)d_in[2];
    const float* W2            = (const float*)d_in[3];
    const float* b2            = (const float*)d_in[4];
    const int*   buffer_index  = (const int*)d_in[5];
    const int*   stack_indexes = (const int*)d_in[6];
    const int*   stack_len     = (const int*)d_in[7];
    float*       out           = (float*)d_out;

    unsigned short* bfrag = (unsigned short*)d_ws;   // 156*64*8*2 = 159,744 B

    prep_w1<<<39, 256, 0, stream>>>(W1, bfrag);
    parser_main<<<Bq / MB, NTHR, 0, stream>>>(
        buffer, bfrag, b1, W2, b2, buffer_index, stack_indexes, stack_len, out);
}

// Round 8
// 14.607 us; speedup vs baseline: 5.5639x; 1.0675x over previous
//
#include <hip/hip_runtime.h>

// TBSyntaxParser v8: ONE kernel, no prep node, no grid sync. Each wave stages
// its own 16-column W1 slab(s) into wave-private LDS (transposed, bf16,
// (k,k+1)-pair dwords) -> B-fragments via single ds_read_b128 each. Wave-
// private staging needs no __syncthreads, so the in-flight X-gather is never
// drained early. W1 loads issue first (in-order vmcnt: pack waits only W1);
// gather issues after and is drained by the one barrier.
// B=4096, L=128, D=60, X=360(k, pad 384), HID=200(n), OUT=3.
// d_out = [out (B*3) | legal (B*3)] f32.

#define Bq    4096
#define Lq    128
#define Dq    60
#define HIDq  200
#define ONUM  3
#define KTN   12        // k-tiles (384/32)
#define MB    16        // states per block (MFMA M)
#define NTHR  512       // 8 waves
#define SLABW 196       // words per n-column in wbuf (192 k-pairs + 4 pad; %32=4 -> bank spread, %4=0 -> 16B align)

typedef short bf16x8 __attribute__((ext_vector_type(8)));
typedef float f32x4  __attribute__((ext_vector_type(4)));

__device__ __forceinline__ unsigned int rhu(float f) {
    union { float f; unsigned int u; } x; x.f = f;
    return x.u + 0x8000u;                      // round-half-up into bf16 slot
}
// pack two rounded floats -> (bf16(hi)<<16) | bf16(lo) in one v_perm_b32
__device__ __forceinline__ int pack2(float lo, float hi) {
    return (int)__builtin_amdgcn_perm(rhu(hi), rhu(lo), 0x07060302u);
}

__global__ __launch_bounds__(NTHR, 1) void parser_fused(
    const float* __restrict__ buffer,
    const float* __restrict__ W1,
    const float* __restrict__ b1,
    const float* __restrict__ W2,
    const float* __restrict__ b2,
    const int*   __restrict__ buffer_index,
    const int*   __restrict__ stack_indexes,
    const int*   __restrict__ stack_len,
    float*       __restrict__ out)
{
    __shared__ unsigned short Afrag[KTN * 64 * 8];     // 12 KiB, A-fragment packed
    __shared__ unsigned int   wbuf[8][16 * SLABW];     // 100.4 KiB wave-private W1 slabs
    __shared__ float          psum[8][MB][ONUM];       // 1.5 KiB wave partials

    const int t  = threadIdx.x;
    const int w  = t >> 6;
    const int l  = t & 63;
    const int s0 = blockIdx.x * MB;

    const bool hasB1 = (w < 5);

    // ---- W1 slab staging (wave-private; issued FIRST so pack waits only W1) ----
    // slab for n-tile nt: wbuf[w][(nl)*SLABW + k2] = pack(W1[2k2][nt*16+nl], W1[2k2+1][...])
    #define STAGE_SLAB(ntile)                                                      \
    {                                                                              \
        _Pragma("unroll")                                                          \
        for (int it = 0; it < 12; ++it) {                                          \
            int j = it * 64 + l;                                                   \
            if (it < 11 || l < 16) {      /* j < 720 */                            \
                int k2 = j >> 2, nq = j & 3;                                       \
                int nb = (ntile) * 16 + nq * 4;                                    \
                float4 v0 = {0.f,0.f,0.f,0.f}, v1 = {0.f,0.f,0.f,0.f};             \
                if (nb < HIDq) {                                                   \
                    const float* p = W1 + (size_t)(2 * k2) * HIDq + nb;            \
                    v0 = *(const float4*)p;                                        \
                    v1 = *(const float4*)(p + HIDq);                               \
                }                                                                  \
                wbuf[w][(nq*4+0)*SLABW + k2] = (unsigned)pack2(v0.x, v1.x);        \
                wbuf[w][(nq*4+1)*SLABW + k2] = (unsigned)pack2(v0.y, v1.y);        \
                wbuf[w][(nq*4+2)*SLABW + k2] = (unsigned)pack2(v0.z, v1.z);        \
                wbuf[w][(nq*4+3)*SLABW + k2] = (unsigned)pack2(v0.w, v1.w);        \
            }                                                                      \
        }                                                                          \
    }

    // zero the k-pad words k2 in [180,192) for all 16 columns (192 words, 3/lane)
    #pragma unroll
    for (int z = 0; z < 3; ++z) {
        int idx = z * 64 + l;
        wbuf[w][(idx / 12) * SLABW + 180 + (idx % 12)] = 0u;
    }

    STAGE_SLAB(w)                       // slab 0: n-tile w (n in [16w,16w+16))

    // ---- B0 fragments: one ds_read_b128 each (same-wave lgkm ordering, no barrier) ----
    bf16x8 B0[KTN], B1[KTN];
    #pragma unroll
    for (int kt = 0; kt < KTN; ++kt)
        B0[kt] = *((const bf16x8*)&wbuf[w][(l & 15) * SLABW + kt * 16 + ((l >> 4) << 2)]);

    if (hasB1) {
        STAGE_SLAB(8 + w)               // slab 1 overwrites slab 0 region (WAR via lgkm)
        #pragma unroll
        for (int kt = 0; kt < KTN; ++kt)
            B1[kt] = *((const bf16x8*)&wbuf[w][(l & 15) * SLABW + kt * 16 + ((l >> 4) << 2)]);
    }
    #undef STAGE_SLAB

    // ---- epilogue constants ----
    const int  n0   = w * 16 + (l & 15);             // <= 127, always valid
    const int  n1   = (8 + w) * 16 + (l & 15);
    const bool n1ok = n1 < HIDq;
    float bb0 = b1[n0];
    float w20 = W2[n0 * ONUM + 0], w21 = W2[n0 * ONUM + 1], w22 = W2[n0 * ONUM + 2];
    float bb1 = 0.f, w23 = 0.f, w24 = 0.f, w25 = 0.f;
    if (hasB1 && n1ok) {
        bb1 = b1[n1];
        w23 = W2[n1 * ONUM + 0]; w24 = W2[n1 * ONUM + 1]; w25 = W2[n1 * ONUM + 2];
    }

    // ---- gather X: 1440 float4 jobs over 512 threads (issued after W1 loads) ----
    // X[s][k] -> kt=k>>5, lane = s + ((k&31)>>3)*16, e = k&7  (k0%4==0 per job)
    #define GATHER_JOB(i)                                                        \
    {                                                                            \
        int s = (i) / 90, r = (i) % 90, seg = r / 15, f = r % 15;                \
        int row = (seg < 3) ? (buffer_index[s0 + s] + seg)                       \
                            : stack_indexes[(s0 + s) * 3 + (seg - 3)];           \
        float4 v = ((const float4*)(buffer + ((size_t)(s0 + s) * Lq + row) * Dq))[f]; \
        int k0   = seg * 60 + f * 4;                                             \
        int kt   = k0 >> 5;                                                      \
        int lane = s + (((k0 & 31) >> 3) << 4);                                  \
        uint2 pk;                                                                \
        pk.x = (unsigned)pack2(v.x, v.y);                                        \
        pk.y = (unsigned)pack2(v.z, v.w);                                        \
        *((uint2*)&Afrag[(size_t)(kt * 64 + lane) * 8 + (k0 & 7)]) = pk;         \
    }
    GATHER_JOB(t)
    GATHER_JOB(t + 512)
    if (t < 416) GATHER_JOB(t + 1024)
    #undef GATHER_JOB

    // zero k-pad of Afrag kt=11 (lanes 16..63 hold k in [360,384))
    if (t < 48) {
        f32x4 z = {0.f, 0.f, 0.f, 0.f};
        *((f32x4*)&Afrag[(size_t)(11 * 64 + 16 + t) * 8]) = z;
    }

    // ---- legal mask (independent of MLP) ----
    if (t < MB * ONUM) {
        int s = t / ONUM, o = t % ONUM;
        int bi = buffer_index[s0 + s];
        int sl = stack_len[s0 + s];
        float lg;
        if (o == 0)      lg = (bi + 3 >= Lq) ? 0.f : 1.f;
        else if (o == 1) lg = (sl <= 3)      ? 0.f : 1.f;
        else             lg = (sl <= 4)      ? 0.f : 1.f;
        out[(size_t)Bq * ONUM + (size_t)(s0 + s) * ONUM + o] = lg;
    }
    __syncthreads();

    // ---- layer 1 MFMA: A from LDS, B in registers ----
    f32x4 acc0 = {}, acc1 = {};
    #pragma unroll
    for (int kt = 0; kt < KTN; ++kt) {
        bf16x8 a = *((const bf16x8*)&Afrag[(size_t)(kt * 64 + l) * 8]);
        acc0 = __builtin_amdgcn_mfma_f32_16x16x32_bf16(a, B0[kt], acc0, 0, 0, 0);
        if (hasB1)
            acc1 = __builtin_amdgcn_mfma_f32_16x16x32_bf16(a, B1[kt], acc1, 0, 0, 0);
    }

    // ---- fused epilogue: bias + ReLU + layer-2 partials in-register ----
    // lane holds hid_pre[s = (l>>4)*4 + r][j = nt*16 + (l&15)] in acc[r]
    float p[ONUM][4];
    #pragma unroll
    for (int o = 0; o < ONUM; ++o)
        #pragma unroll
        for (int r = 0; r < 4; ++r) p[o][r] = 0.f;

    #pragma unroll
    for (int r = 0; r < 4; ++r) {
        float h = acc0[r] + bb0; h = h > 0.f ? h : 0.f;
        p[0][r] = fmaf(h, w20, p[0][r]);
        p[1][r] = fmaf(h, w21, p[1][r]);
        p[2][r] = fmaf(h, w22, p[2][r]);
    }
    if (hasB1) {
        #pragma unroll
        for (int r = 0; r < 4; ++r) {
            float h = acc1[r] + bb1; h = h > 0.f ? h : 0.f;   // consts are 0 if n1>=200
            p[0][r] = fmaf(h, w23, p[0][r]);
            p[1][r] = fmaf(h, w24, p[1][r]);
            p[2][r] = fmaf(h, w25, p[2][r]);
        }
    }

    // butterfly-reduce over the 16-lane j-group
    #pragma unroll
    for (int d = 1; d < 16; d <<= 1) {
        #pragma unroll
        for (int o = 0; o < ONUM; ++o)
            #pragma unroll
            for (int r = 0; r < 4; ++r)
                p[o][r] += __shfl_xor(p[o][r], d, 64);
    }
    if ((l & 15) == 0) {
        #pragma unroll
        for (int r = 0; r < 4; ++r) {
            int s = ((l >> 4) << 2) + r;
            #pragma unroll
            for (int o = 0; o < ONUM; ++o) psum[w][s][o] = p[o][r];
        }
    }
    __syncthreads();

    // ---- combine 8 wave-partials + bias ----
    if (t < MB * ONUM) {
        int s = t / ONUM, o = t % ONUM;
        float v = b2[o];
        #pragma unroll
        for (int w8 = 0; w8 < 8; ++w8) v += psum[w8][s][o];
        out[(size_t)(s0 + s) * ONUM + o] = v;
    }
}

extern "C" void kernel_launch(void* const* d_in, const int* in_sizes, int n_in,
                              void* d_out, int out_size, void* d_ws, size_t ws_size,
                              hipStream_t stream) {
    const float* buffer        = (const float*)d_in[0];
    const float* W1            = (const float*)d_in[1];
    const float* b1            = (const float*)d_in[2];
    const float* W2            = (const float*)d_in[3];
    const float* b2            = (const float*)d_in[4];
    const int*   buffer_index  = (const int*)d_in[5];
    const int*   stack_indexes = (const int*)d_in[6];
    const int*   stack_len     = (const int*)d_in[7];
    float*       out           = (float*)d_out;

    parser_fused<<<Bq / MB, NTHR, 0, stream>>>(
        buffer, W1, b1, W2, b2, buffer_index, stack_indexes, stack_len, out);
}